// Round 3
// baseline (83.367 us; speedup 1.0000x reference)
//
#include <hip/hip_runtime.h>
#include <math.h>

#define NP 196   // 14*14 patches per image
#define FEAT 784

// Fully fused: conv2x2/s2 -> 4-qubit quantum filter -> FC(784->10) -> log_softmax.
// One block (256 threads) per image.
//   Phase 1: threads 0..195 simulate one patch each (16-amp statevector in
//            registers), feats written to LDS in transposed [c*196+hw] layout.
//   Phase 2: wave 0 only — float4 FC + single 60-shuffle reduction tree.
// Rationale: __shfl == ds_bpermute on the shared LDS pipe; doing the
// reduction in 4 waves cost 240 DS wave-instr/block (~10.8 us/CU at 16
// blocks/CU). One wave + vectorized W loads cuts DS/block to ~80.

__device__ __forceinline__ void apply_ry(float* s, const int mask, float c, float sn) {
#pragma unroll
    for (int i = 0; i < 16; ++i) {
        if (!(i & mask)) {
            float a = s[i], b = s[i | mask];
            s[i]        = c * a - sn * b;
            s[i | mask] = sn * a + c * b;
        }
    }
}

__device__ __forceinline__ void apply_cnot(float* s, const int mc, const int mt) {
#pragma unroll
    for (int i = 0; i < 16; ++i) {
        if ((i & mc) && !(i & mt)) {
            float t = s[i];
            s[i]      = s[i | mt];
            s[i | mt] = t;
        }
    }
}

__global__ void __launch_bounds__(256)
quanv_fused(const float* __restrict__ x,    // [B,1,28,28]
            const float* __restrict__ cw,   // [4,1,2,2]
            const float* __restrict__ cb,   // [4]
            const float* __restrict__ ang,  // [5]
            const float* __restrict__ W,    // [10,784]
            const float* __restrict__ bias, // [10]
            float* __restrict__ out) {      // [B,10]
    __shared__ float feats[FEAT];

    const int b   = blockIdx.x;
    const int tid = threadIdx.x;

    // ---------------- Phase 1: conv + quantum filter ----------------
    if (tid < NP) {
        const int i = tid / 14;
        const int j = tid - i * 14;

        const float* xp = x + b * 784 + (2 * i) * 28 + 2 * j;
        const float2 r0 = *(const float2*)(xp);
        const float2 r1 = *(const float2*)(xp + 28);

        float cs[4], sn[4];
#pragma unroll
        for (int c = 0; c < 4; ++c) {
            float th = cw[c * 4 + 0] * r0.x + cw[c * 4 + 1] * r0.y +
                       cw[c * 4 + 2] * r1.x + cw[c * 4 + 3] * r1.y + cb[c];
            float h = 0.5f * th;
            cs[c] = __cosf(h);
            sn[c] = __sinf(h);
        }

        // product state after 4 encoder RYs: bit3=q0, bit2=q1, bit1=q2, bit0=q3
        float s[16];
        {
            float v00 = cs[0] * cs[1], v01 = cs[0] * sn[1];
            float v10 = sn[0] * cs[1], v11 = sn[0] * sn[1];
            float w00 = cs[2] * cs[3], w01 = cs[2] * sn[3];
            float w10 = sn[2] * cs[3], w11 = sn[2] * sn[3];
            s[ 0] = v00 * w00; s[ 1] = v00 * w01; s[ 2] = v00 * w10; s[ 3] = v00 * w11;
            s[ 4] = v01 * w00; s[ 5] = v01 * w01; s[ 6] = v01 * w10; s[ 7] = v01 * w11;
            s[ 8] = v10 * w00; s[ 9] = v10 * w01; s[10] = v10 * w10; s[11] = v10 * w11;
            s[12] = v11 * w00; s[13] = v11 * w01; s[14] = v11 * w10; s[15] = v11 * w11;
        }

        // learned layer: RY0, RY1, CNOT(0,1), RY2, CNOT(1,2), RY3, CNOT(2,3), RY0
        float a0 = 0.5f * ang[0], a1 = 0.5f * ang[1], a2 = 0.5f * ang[2],
              a3 = 0.5f * ang[3], a4 = 0.5f * ang[4];
        apply_ry  (s, 8, __cosf(a0), __sinf(a0));
        apply_ry  (s, 4, __cosf(a1), __sinf(a1));
        apply_cnot(s, 8, 4);
        apply_ry  (s, 2, __cosf(a2), __sinf(a2));
        apply_cnot(s, 4, 2);
        apply_ry  (s, 1, __cosf(a3), __sinf(a3));
        apply_cnot(s, 2, 1);
        apply_ry  (s, 8, __cosf(a4), __sinf(a4));

        float ez0 = 0.f, ez1 = 0.f, ez2 = 0.f, ez3 = 0.f;
#pragma unroll
        for (int idx = 0; idx < 16; ++idx) {
            float p = s[idx] * s[idx];
            ez0 += (idx & 8) ? -p : p;
            ez1 += (idx & 4) ? -p : p;
            ez2 += (idx & 2) ? -p : p;
            ez3 += (idx & 1) ? -p : p;
        }

        feats[0 * NP + tid] = ez0;
        feats[1 * NP + tid] = ez1;
        feats[2 * NP + tid] = ez2;
        feats[3 * NP + tid] = ez3;
    }

    __syncthreads();

    // ---------------- Phase 2: FC 784 -> 10 + log_softmax (wave 0 only) ------
    if (tid < 64) {
        const int lane = tid;
        float acc[10];
#pragma unroll
        for (int k = 0; k < 10; ++k) acc[k] = 0.f;

        // 196 float4 chunks; lane handles c = lane, lane+64, lane+128, lane+192
        for (int c = lane; c < NP; c += 64) {
            const float4 f = *(const float4*)&feats[c * 4];
            const float* wp = W + c * 4;
#pragma unroll
            for (int k = 0; k < 10; ++k) {
                const float4 w = *(const float4*)(wp + k * FEAT);
                float d = fmaf(f.x, w.x, fmaf(f.y, w.y, fmaf(f.z, w.z, f.w * w.w)));
                acc[k] += d;
            }
        }

#pragma unroll
        for (int k = 0; k < 10; ++k) {
#pragma unroll
            for (int off = 32; off > 0; off >>= 1)
                acc[k] += __shfl_down(acc[k], off, 64);
        }

        if (lane == 0) {
            float l[10], m = -INFINITY;
#pragma unroll
            for (int k = 0; k < 10; ++k) {
                l[k] = acc[k] + bias[k];
                m = fmaxf(m, l[k]);
            }
            float ssum = 0.f;
#pragma unroll
            for (int k = 0; k < 10; ++k) ssum += __expf(l[k] - m);
            float ls = __logf(ssum) + m;
            float* o = out + b * 10;
#pragma unroll
            for (int k = 0; k < 10; ++k) o[k] = l[k] - ls;
        }
    }
}

extern "C" void kernel_launch(void* const* d_in, const int* in_sizes, int n_in,
                              void* d_out, int out_size, void* d_ws, size_t ws_size,
                              hipStream_t stream) {
    const float* x      = (const float*)d_in[0];
    const float* conv_w = (const float*)d_in[1];
    const float* conv_b = (const float*)d_in[2];
    const float* angles = (const float*)d_in[3];
    const float* fc_w   = (const float*)d_in[4];
    const float* fc_b   = (const float*)d_in[5];
    float* out = (float*)d_out;

    int B = in_sizes[0] / 784;  // 4096
    quanv_fused<<<B, 256, 0, stream>>>(x, conv_w, conv_b, angles, fc_w, fc_b, out);
}

// Round 4
// 77.163 us; speedup vs baseline: 1.0804x; 1.0804x over previous
//
#include <hip/hip_runtime.h>
#include <math.h>

#define NP 196   // 14*14 patches per image
#define FEAT 784

// Fully fused: conv2x2/s2 -> 4-qubit quantum filter -> FC(784->10) -> log_softmax.
// One block (256 threads) per image.
//
// Circuit algebra (verified against reference op order):
//   enc RY(x_w) ; RY0(a0) RY1(a1) CNOT(0,1) RY2(a2) CNOT(1,2) RY3(a3)
//   CNOT(2,3) RY0(a4)
// == product state with theta_w = x_w + a_w  ->  CNOT(0,1) CNOT(1,2) CNOT(2,3)
//    -> RY0(a4) -> measure Z.
// (RY merges on same wire; RY2/RY3 commute back past CNOTs not touching them;
//  final RY0(a4) cannot commute past CNOT(0,1)'s control.)
// The final RY0 is folded into measurement: per wire-0 pair (u,v),
//   <Z0> contrib = cos(a4)(u^2-v^2) - sin(a4)*2uv;  Z1..Z3 invariant (u^2+v^2
// preserved by rotation). CNOTs are compile-time index renames (zero VALU).

__device__ __forceinline__ void apply_cnot(float* s, const int mc, const int mt) {
#pragma unroll
    for (int i = 0; i < 16; ++i) {
        if ((i & mc) && !(i & mt)) {
            float t = s[i];
            s[i]      = s[i | mt];
            s[i | mt] = t;
        }
    }
}

__global__ void __launch_bounds__(256)
quanv_fused(const float* __restrict__ x,    // [B,1,28,28]
            const float* __restrict__ cw,   // [4,1,2,2]
            const float* __restrict__ cb,   // [4]
            const float* __restrict__ ang,  // [5]
            const float* __restrict__ W,    // [10,784]
            const float* __restrict__ bias, // [10]
            float* __restrict__ out) {      // [B,10]
    __shared__ float feats[FEAT];

    const int b   = blockIdx.x;
    const int tid = threadIdx.x;

    // ---------------- Phase 1: conv + quantum filter ----------------
    if (tid < NP) {
        const int i = tid / 14;
        const int j = tid - i * 14;

        const float* xp = x + b * 784 + (2 * i) * 28 + 2 * j;
        const float2 r0 = *(const float2*)(xp);
        const float2 r1 = *(const float2*)(xp + 28);

        // theta_w = conv_w(patch) + cb_w + ang_w  (RY merge), half-angle sincos
        float cs[4], sn[4];
#pragma unroll
        for (int c = 0; c < 4; ++c) {
            float th = cw[c * 4 + 0] * r0.x + cw[c * 4 + 1] * r0.y +
                       cw[c * 4 + 2] * r1.x + cw[c * 4 + 3] * r1.y +
                       (cb[c] + ang[c]);
            __sincosf(0.5f * th, &sn[c], &cs[c]);
        }

        // product state: bit3=q0, bit2=q1, bit1=q2, bit0=q3
        float s[16];
        {
            float v00 = cs[0] * cs[1], v01 = cs[0] * sn[1];
            float v10 = sn[0] * cs[1], v11 = sn[0] * sn[1];
            float w00 = cs[2] * cs[3], w01 = cs[2] * sn[3];
            float w10 = sn[2] * cs[3], w11 = sn[2] * sn[3];
            s[ 0] = v00 * w00; s[ 1] = v00 * w01; s[ 2] = v00 * w10; s[ 3] = v00 * w11;
            s[ 4] = v01 * w00; s[ 5] = v01 * w01; s[ 6] = v01 * w10; s[ 7] = v01 * w11;
            s[ 8] = v10 * w00; s[ 9] = v10 * w01; s[10] = v10 * w10; s[11] = v10 * w11;
            s[12] = v11 * w00; s[13] = v11 * w01; s[14] = v11 * w10; s[15] = v11 * w11;
        }

        // CNOT(0,1), CNOT(1,2), CNOT(2,3) — pure register renames when unrolled
        apply_cnot(s, 8, 4);
        apply_cnot(s, 4, 2);
        apply_cnot(s, 2, 1);

        // measurement with final RY0(a4) folded in
        float p[16];
#pragma unroll
        for (int idx = 0; idx < 16; ++idx) p[idx] = s[idx] * s[idx];

        float q[8], d[8], xx[8];
#pragma unroll
        for (int jj = 0; jj < 8; ++jj) {
            q[jj]  = p[jj] + p[jj + 8];        // pair probability (RY0-invariant)
            d[jj]  = p[jj] - p[jj + 8];        // u^2 - v^2
            xx[jj] = s[jj] * s[jj + 8];        // u*v
        }

        // Z1..Z3 from q[j], j bits: b2=wire1, b1=wire2, b0=wire3
        float A = q[0] + q[1], Bq = q[2] + q[3], C = q[4] + q[5], D = q[6] + q[7];
        float ez1 = (A + Bq) - (C + D);
        float ez2 = (A - Bq) + (C - D);
        float ez3 = (q[0] - q[1]) + (q[2] - q[3]) + (q[4] - q[5]) + (q[6] - q[7]);

        float Dsum = ((d[0] + d[1]) + (d[2] + d[3])) + ((d[4] + d[5]) + (d[6] + d[7]));
        float Xsum = ((xx[0] + xx[1]) + (xx[2] + xx[3])) + ((xx[4] + xx[5]) + (xx[6] + xx[7]));
        float ca4, sa4;
        __sincosf(ang[4], &sa4, &ca4);
        float ez0 = ca4 * Dsum - sa4 * (2.0f * Xsum);

        feats[0 * NP + tid] = ez0;
        feats[1 * NP + tid] = ez1;
        feats[2 * NP + tid] = ez2;
        feats[3 * NP + tid] = ez3;
    }

    __syncthreads();

    // ---------------- Phase 2: FC 784 -> 10 + log_softmax (wave 0) ----------
    if (tid < 64) {
        const int lane = tid;
        float acc[10];
#pragma unroll
        for (int k = 0; k < 10; ++k) acc[k] = 0.f;

        for (int c = lane; c < NP; c += 64) {
            const float4 f = *(const float4*)&feats[c * 4];
            const float* wp = W + c * 4;
#pragma unroll
            for (int k = 0; k < 10; ++k) {
                const float4 w = *(const float4*)(wp + k * FEAT);
                acc[k] += fmaf(f.x, w.x, fmaf(f.y, w.y, fmaf(f.z, w.z, f.w * w.w)));
            }
        }

#pragma unroll
        for (int k = 0; k < 10; ++k) {
#pragma unroll
            for (int off = 32; off > 0; off >>= 1)
                acc[k] += __shfl_down(acc[k], off, 64);
        }

        if (lane == 0) {
            float l[10], m = -INFINITY;
#pragma unroll
            for (int k = 0; k < 10; ++k) {
                l[k] = acc[k] + bias[k];
                m = fmaxf(m, l[k]);
            }
            float ssum = 0.f;
#pragma unroll
            for (int k = 0; k < 10; ++k) ssum += __expf(l[k] - m);
            float ls = __logf(ssum) + m;
            float* o = out + b * 10;
#pragma unroll
            for (int k = 0; k < 10; ++k) o[k] = l[k] - ls;
        }
    }
}

extern "C" void kernel_launch(void* const* d_in, const int* in_sizes, int n_in,
                              void* d_out, int out_size, void* d_ws, size_t ws_size,
                              hipStream_t stream) {
    const float* x      = (const float*)d_in[0];
    const float* conv_w = (const float*)d_in[1];
    const float* conv_b = (const float*)d_in[2];
    const float* angles = (const float*)d_in[3];
    const float* fc_w   = (const float*)d_in[4];
    const float* fc_b   = (const float*)d_in[5];
    float* out = (float*)d_out;

    int B = in_sizes[0] / 784;  // 4096
    quanv_fused<<<B, 256, 0, stream>>>(x, conv_w, conv_b, angles, fc_w, fc_b, out);
}